// Round 2
// baseline (189.189 us; speedup 1.0000x reference)
//
#include <hip/hip_runtime.h>

typedef __attribute__((ext_vector_type(8))) short bf16x8;
typedef __attribute__((ext_vector_type(4))) float f32x4;

__device__ __forceinline__ unsigned short f2bf(float f) {
    unsigned int u = __float_as_uint(f);
    u = (u + 0x7FFFu + ((u >> 16) & 1u)) >> 16;   // round-to-nearest-even
    return (unsigned short)u;
}

// ---------------------------------------------------------------------------
// Kernel 1: partial Wc = w_patch @ [w_reg | w_obj], split over 6 d-chunks.
// grid (6 d-chunks, 12 k-tiles), block 256. Writes part[dc][k][48] fp32.
// ---------------------------------------------------------------------------
__global__ __launch_bounds__(256) void wcomb_partial(
        const float* __restrict__ wp, const float* __restrict__ wreg,
        const float* __restrict__ wobj, float* __restrict__ part) {
    __shared__ float Al[64][132];   // 64 k-rows x 128 d (pad 132)
    __shared__ float Bl[48][132];   // 48 n x 128 d (transposed, pad 132)
    const int t  = threadIdx.x;
    const int d0 = blockIdx.x * 128;
    const int k0 = blockIdx.y * 64;

    #pragma unroll
    for (int i = 0; i < 8; ++i) {                       // A: 64x128 floats
        int e = i * 256 + t;
        int row = e >> 5, dq = e & 31;
        *(f32x4*)&Al[row][dq * 4] =
            *(const f32x4*)&wp[(size_t)(k0 + row) * 768 + d0 + dq * 4];
    }
    #pragma unroll
    for (int i = 0; i < 24; ++i) {                      // B: 128x48 scalars
        int e = i * 256 + t;
        int d = e / 48, n = e - d * 48;
        float v = 0.f;
        if (n < 36)      v = wreg[(size_t)(d0 + d) * 36 + n];
        else if (n < 45) v = wobj[(size_t)(d0 + d) * 9 + (n - 36)];
        Bl[n][d] = v;
    }
    __syncthreads();

    const int r0 = (t & 15) * 4;      // 4 k-rows per thread
    const int n0 = (t >> 4) * 3;      // 3 n-cols per thread
    float acc[4][3] = {};
    for (int ds = 0; ds < 32; ++ds) {
        f32x4 a[4], bv[3];
        #pragma unroll
        for (int i = 0; i < 4; ++i) a[i] = *(const f32x4*)&Al[r0 + i][ds * 4];
        #pragma unroll
        for (int j = 0; j < 3; ++j) bv[j] = *(const f32x4*)&Bl[n0 + j][ds * 4];
        #pragma unroll
        for (int i = 0; i < 4; ++i)
            #pragma unroll
            for (int j = 0; j < 3; ++j)
                acc[i][j] += a[i].x * bv[j].x + a[i].y * bv[j].y
                           + a[i].z * bv[j].z + a[i].w * bv[j].w;
    }
    #pragma unroll
    for (int i = 0; i < 4; ++i)
        #pragma unroll
        for (int j = 0; j < 3; ++j)
            part[((size_t)blockIdx.x * 768 + k0 + r0 + i) * 48 + n0 + j] = acc[i][j];
}

// ---------------------------------------------------------------------------
// Kernel 2: reduce 6 partial slabs -> Wc_t bf16, TRANSPOSED [48 n][768 k]
// grid (3, 48), block 256.
// ---------------------------------------------------------------------------
__global__ __launch_bounds__(256) void wcomb_reduce(
        const float* __restrict__ part, unsigned short* __restrict__ wct) {
    const int k = blockIdx.x * 256 + threadIdx.x;   // 0..767
    const int n = blockIdx.y;                       // 0..47
    float s = 0.f;
    if (n < 45) {
        #pragma unroll
        for (int dc = 0; dc < 6; ++dc) s += part[((size_t)dc * 768 + k) * 48 + n];
    }
    wct[(size_t)n * 768 + k] = f2bf(s);
}

// ---------------------------------------------------------------------------
// Kernel 3: main fused GEMM + anchor decode — barrier-free streaming K-loop.
// 2048 waves total; each wave owns a 16-cell M-tile (half an fj-row) and all
// 3 N-tiles (N=48). A-fragments load straight from img (fp32->bf16 in-reg);
// B-fragments straight from L2-resident wct. 1-deep register prefetch keeps
// vmcnt > 0 at every MFMA. LDS only for per-wave epilogue transpose.
// grid 512, block 256 (4 waves).
// ---------------------------------------------------------------------------
__global__ __launch_bounds__(256) void detector_main(
        const float* __restrict__ img, const unsigned short* __restrict__ wct,
        const float* __restrict__ breg, const float* __restrict__ bobj,
        float* __restrict__ out) {
    __shared__ float Co[64][49];           // 4 waves x 16 cells x 48 (+pad)

    const int t    = threadIdx.x;
    const int lane = t & 63;
    const int wid  = t >> 6;
    const int cl   = lane & 15;
    const int q    = lane >> 4;
    const int wg   = blockIdx.x * 4 + wid;   // 0..2047 wave-tiles
    const int fj0  = (wg & 1) * 16;
    const int fi   = (wg >> 1) & 31;
    const int b    = wg >> 6;

    // A: lane (cl,q) supplies A[m=cl][k=q*8+j]; for k-block kk (32 k each):
    //   c = kk>>3, p = (kk&7)*2 + (q>>1), pix0 = (q&1)*8, fj = fj0+cl.
    const float* ap = img + (size_t)b * 786432
        + (size_t)(fi * 16 + (q >> 1)) * 512 + (fj0 + cl) * 16 + (q & 1) * 8;
    // B: lane (cl,q) supplies B[n=nt*16+cl][k=q*8+j]; wct is [48][768] bf16.
    const unsigned short* bp = wct + cl * 768 + q * 8;

    f32x4 acc0 = {0.f,0.f,0.f,0.f}, acc1 = acc0, acc2 = acc0;

    // prologue loads (kk = 0)
    f32x4 ca0 = *(const f32x4*)ap;
    f32x4 ca1 = *(const f32x4*)(ap + 4);
    bf16x8 cb0 = *(const bf16x8*)(bp);
    bf16x8 cb1 = *(const bf16x8*)(bp + 12288);
    bf16x8 cb2 = *(const bf16x8*)(bp + 24576);

    #pragma unroll 4
    for (int kk = 0; kk < 24; ++kk) {
        // issue next iteration's 5 loads BEFORE consuming current data,
        // so the MFMA's implicit waitcnt leaves them in flight (vmcnt=5).
        const int astep = ((kk & 7) == 7) ? 254976 : 1024;   // row+2 or channel hop
        const float* nap = (kk == 23) ? ap : ap + astep;
        const unsigned short* nbp = (kk == 23) ? bp : bp + 32;
        f32x4 na0 = *(const f32x4*)nap;
        f32x4 na1 = *(const f32x4*)(nap + 4);
        bf16x8 nb0 = *(const bf16x8*)(nbp);
        bf16x8 nb1 = *(const bf16x8*)(nbp + 12288);
        bf16x8 nb2 = *(const bf16x8*)(nbp + 24576);

        bf16x8 af;
        af[0] = (short)f2bf(ca0.x); af[1] = (short)f2bf(ca0.y);
        af[2] = (short)f2bf(ca0.z); af[3] = (short)f2bf(ca0.w);
        af[4] = (short)f2bf(ca1.x); af[5] = (short)f2bf(ca1.y);
        af[6] = (short)f2bf(ca1.z); af[7] = (short)f2bf(ca1.w);
        acc0 = __builtin_amdgcn_mfma_f32_16x16x32_bf16(af, cb0, acc0, 0, 0, 0);
        acc1 = __builtin_amdgcn_mfma_f32_16x16x32_bf16(af, cb1, acc1, 0, 0, 0);
        acc2 = __builtin_amdgcn_mfma_f32_16x16x32_bf16(af, cb2, acc2, 0, 0, 0);

        ap = nap; bp = nbp;
        ca0 = na0; ca1 = na1; cb0 = nb0; cb1 = nb1; cb2 = nb2;
    }

    // ---- epilogue: C frags -> per-wave LDS slab (col=cl, row=q*4+r) ----
    #pragma unroll
    for (int r = 0; r < 4; ++r) {
        Co[wid * 16 + q * 4 + r][ 0 + cl] = acc0[r];
        Co[wid * 16 + q * 4 + r][16 + cl] = acc1[r];
        Co[wid * 16 + q * 4 + r][32 + cl] = acc2[r];
    }
    __syncthreads();

    // ---- anchor decode: 16 cells x 9 anchors = 144 rows per wave ----
    for (int rr = lane; rr < 144; rr += 64) {
        int cell = rr / 9, k = rr - cell * 9;    // cell = m (0..15)
        int fj = fj0 + cell;
        float v0 = Co[wid * 16 + cell][4 * k + 0] + breg[4 * k + 0];
        float v1 = Co[wid * 16 + cell][4 * k + 1] + breg[4 * k + 1];
        float v2 = Co[wid * 16 + cell][4 * k + 2] + breg[4 * k + 2];
        float v3 = Co[wid * 16 + cell][4 * k + 3] + breg[4 * k + 3];
        float lg = Co[wid * 16 + cell][36 + k] + bobj[k];
        float obj = 1.f / (1.f + __expf(-lg));
        float wc = (float)(fj * 16) + v0;
        float hc = (float)(fi * 16) + v1;
        float wa = wc + (float)(2 << (k % 3)) * v2;   // BOX_W = 2,4,8 cycling
        float ha = hc + (float)(2 << (k / 3)) * v3;   // BOX_H = 2,2,2,4,4,4,8,8,8
        float* o = out + (size_t)(((b * 32 + fi) * 32 + fj) * 9 + k) * 7;
        o[0] = wc; o[1] = hc; o[2] = wa; o[3] = ha;
        o[4] = (float)b; o[5] = obj; o[6] = (float)k;
    }
}

extern "C" void kernel_launch(void* const* d_in, const int* in_sizes, int n_in,
                              void* d_out, int out_size, void* d_ws, size_t ws_size,
                              hipStream_t stream) {
    const float* img  = (const float*)d_in[0];
    const float* wp   = (const float*)d_in[1];
    const float* wreg = (const float*)d_in[2];
    const float* breg = (const float*)d_in[3];
    const float* wobj = (const float*)d_in[4];
    const float* bobj = (const float*)d_in[5];
    float* out = (float*)d_out;

    float* part = (float*)d_ws;                                     // 884736 B
    unsigned short* wct = (unsigned short*)((char*)d_ws + 6 * 768 * 48 * 4);  // 73728 B

    wcomb_partial<<<dim3(6, 12), 256, 0, stream>>>(wp, wreg, wobj, part);
    wcomb_reduce<<<dim3(3, 48), 256, 0, stream>>>(part, wct);
    detector_main<<<512, 256, 0, stream>>>(img, wct, breg, bobj, out);
}